// Round 4
// baseline (559.915 us; speedup 1.0000x reference)
//
#include <hip/hip_runtime.h>
#include <hip/hip_bf16.h>
#include <math.h>
#include <stdint.h>

// ---------------------------------------------------------------------------
// HMQ MLP: fake-quant(int8) GEMM1 + bias + exact GELU -> fake-quant -> GEMM2
// int8 MFMA (mfma_i32_16x16x64_i8), exact int32 accumulation.
// R4: GEMM1 epilogue transposes C through LDS and stores h16 in STAGED int16
// layout (1KB-contiguous stores) -- R3 wrote row-major 2B-scattered shorts,
// causing 3.3x write amplification (422 MB vs 128 MB) + L3 thrash (210 MB
// fetch). quant_h is now a pure streaming convert (same linear index).
// ---------------------------------------------------------------------------

typedef int    v4i    __attribute__((ext_vector_type(4)));
typedef short  short8 __attribute__((ext_vector_type(8)));
typedef int8_t char8  __attribute__((ext_vector_type(8)));

#define QMAXF 127.0f

__device__ __forceinline__ void load_lds16(const void* g, void* l) {
    __builtin_amdgcn_global_load_lds(
        (__attribute__((address_space(1))) void*)(g),
        (__attribute__((address_space(3))) void*)(l),
        16, 0, 0);
}

// ---------------- init: zero the scale slots ----------------
__global__ void init_slots(unsigned int* slots) {
    if (threadIdx.x < 8) slots[threadIdx.x] = 0u;
}

// ---------------- absmax reduction (fp32, float4) ----------------
__global__ void absmax_kernel(const float4* __restrict__ t, int n4,
                              unsigned int* __restrict__ slot) {
    float m = 0.f;
    int stride = gridDim.x * blockDim.x;
    for (int i = blockIdx.x * blockDim.x + threadIdx.x; i < n4; i += stride) {
        float4 v = t[i];
        m = fmaxf(m, fmaxf(fmaxf(fabsf(v.x), fabsf(v.y)),
                           fmaxf(fabsf(v.z), fabsf(v.w))));
    }
#pragma unroll
    for (int off = 32; off > 0; off >>= 1)
        m = fmaxf(m, __shfl_xor(m, off));
    if ((threadIdx.x & 63) == 0)
        atomicMax(slot, __float_as_uint(m));  // vals >= 0: uint order == float order
}

// ---------------- quantize fp32 -> staged int8 ----------------
// One wave per 1KB block (rb, kc): lane L handles row15=L&15, chunk=L>>4.
__global__ void quant_stage_kernel(const float* __restrict__ x, int kshift,
                                   int nblocks, const float* __restrict__ slot,
                                   int8_t* __restrict__ q) {
    const float s = fmaxf(*slot, 1e-8f) / QMAXF;
    const int lane = threadIdx.x & 63;
    const int wave0 = (blockIdx.x * blockDim.x + threadIdx.x) >> 6;
    const int nwaves = (gridDim.x * blockDim.x) >> 6;
    const int nkb = 1 << kshift;  // K/64
    for (int wb = wave0; wb < nblocks; wb += nwaves) {
        const int rb = wb >> kshift;
        const int kc = wb & (nkb - 1);
        const int row = rb * 16 + (lane & 15);
        const int k0  = kc * 64 + (lane >> 4) * 16;
        const float4* src = (const float4*)(x + ((size_t)row << (kshift + 6)) + k0);
        int8_t tmp[16];
#pragma unroll
        for (int j = 0; j < 4; j++) {
            float4 v = src[j];
            tmp[j*4+0] = (int8_t)fminf(fmaxf(rintf(v.x / s), -127.f), 127.f);
            tmp[j*4+1] = (int8_t)fminf(fmaxf(rintf(v.y / s), -127.f), 127.f);
            tmp[j*4+2] = (int8_t)fminf(fmaxf(rintf(v.z / s), -127.f), 127.f);
            tmp[j*4+3] = (int8_t)fminf(fmaxf(rintf(v.w / s), -127.f), 127.f);
        }
        *(int4*)(q + (size_t)wb * 1024 + lane * 16) = *(const int4*)tmp;
    }
}

// ---------------- streaming: staged int16 h -> staged int8 hq ----------
// Same linear index on both sides; tile scale constant per 1K block.
__global__ void quant_h_kernel(const short8* __restrict__ h16s,
                               const float* __restrict__ tilescale,
                               const float* __restrict__ hslot,
                               char8* __restrict__ q, int n8) {
    const float sh = fmaxf(*hslot, 1e-8f) / QMAXF;
    int stride = gridDim.x * blockDim.x;
    for (int i = blockIdx.x * blockDim.x + threadIdx.x; i < n8; i += stride) {
        const int blk = i >> 7;            // (i*8)/1024
        const int rb = blk >> 6, kc = blk & 63;
        const int tile = (rb >> 3) * 32 + (kc >> 1);
        const float f = tilescale[tile] / (32767.f * sh);
        short8 v = h16s[i];
        char8 o;
#pragma unroll
        for (int j = 0; j < 8; j++)
            o[j] = (int8_t)fminf(fmaxf(rintf((float)v[j] * f), -127.f), 127.f);
        q[i] = o;
    }
}

// ---------------- int8 GEMM on staged operands ----------------
#define EPI_G1_STORE_I16 0   // g=gelu(..); tilemax; store staged int16
#define EPI_G1_MAXONLY   1   // g=gelu(..); atomicMax only (fallback)
#define EPI_G1_QUANT     2   // g=gelu(..); store staged int8 (fallback)
#define EPI_G2_OUT       3   // out = acc*s + b; store fp32 row-major

template <int EPI>
__global__ __launch_bounds__(256, 4) void gemm_i8_kernel(
    const int8_t* __restrict__ A, const int8_t* __restrict__ B,
    int N, int K,
    const float* __restrict__ slotA, const float* __restrict__ slotB,
    const float* __restrict__ bias,
    int16_t* __restrict__ h16_out,        // EPI 0 (staged layout)
    float* __restrict__ tilescale,        // EPI 0
    unsigned int* __restrict__ maxslot,   // EPI 0/1
    const float* __restrict__ hslot,      // EPI 2
    int8_t* __restrict__ q_out,           // EPI 2
    float* __restrict__ out)              // EPI 3
{
    __shared__ __align__(16) int8_t smem[2][2][8192];  // [buf][A/B]
    __shared__ float red[4];
    __shared__ float ts_sh;

    const int tid  = threadIdx.x;
    const int lane = tid & 63;
    const int wv   = tid >> 6;
    const int wm   = wv & 1;
    const int wn   = wv >> 1;

    const int bm = blockIdx.x * 128;   // M fast: co-resident blocks share B tiles
    const int bn = blockIdx.y * 128;
    const int nkb = K >> 6;

    const float sAB = (fmaxf(*slotA, 1e-8f) / QMAXF) *
                      (fmaxf(*slotB, 1e-8f) / QMAXF);

    v4i acc[4][4] = {};

    const size_t rbstride = (size_t)nkb * 1024;
    const int8_t* gA = A + (size_t)((bm >> 4) + wv * 2) * rbstride + lane * 16;
    const int8_t* gB = B + (size_t)((bn >> 4) + wv * 2) * rbstride + lane * 16;
    const int ldsoff = wv * 2048 + lane * 16;

    // prologue: fill buf 0
    load_lds16(gA,            &smem[0][0][ldsoff]);
    load_lds16(gA + rbstride, &smem[0][0][ldsoff + 1024]);
    load_lds16(gB,            &smem[0][1][ldsoff]);
    load_lds16(gB + rbstride, &smem[0][1][ldsoff + 1024]);
    gA += 1024; gB += 1024;

    for (int kt = 0; kt < nkb; kt++) {
        __syncthreads();
        if (kt + 1 < nkb) {
            const int nb = (kt + 1) & 1;
            load_lds16(gA,            &smem[nb][0][ldsoff]);
            load_lds16(gA + rbstride, &smem[nb][0][ldsoff + 1024]);
            load_lds16(gB,            &smem[nb][1][ldsoff]);
            load_lds16(gB + rbstride, &smem[nb][1][ldsoff + 1024]);
            gA += 1024; gB += 1024;
        }
        const int cb = kt & 1;
        v4i af[4], bf[4];
#pragma unroll
        for (int mi = 0; mi < 4; mi++)
            af[mi] = *(const v4i*)&smem[cb][0][(wm * 4 + mi) * 1024 + lane * 16];
#pragma unroll
        for (int ni = 0; ni < 4; ni++)
            bf[ni] = *(const v4i*)&smem[cb][1][(wn * 4 + ni) * 1024 + lane * 16];
#pragma unroll
        for (int mi = 0; mi < 4; mi++)
#pragma unroll
            for (int ni = 0; ni < 4; ni++)
                acc[mi][ni] = __builtin_amdgcn_mfma_i32_16x16x64_i8(
                    af[mi], bf[ni], acc[mi][ni], 0, 0, 0);
    }

    // ---------------- epilogue ----------------
    float sc_q = 0.f;
    if constexpr (EPI == EPI_G1_QUANT) sc_q = fmaxf(*hslot, 1e-8f) / QMAXF;
    float lmax = 0.f;

    // phase 1: dequant + bias (+ GELU); park result bits back into acc regs
#pragma unroll
    for (int mi = 0; mi < 4; mi++) {
#pragma unroll
        for (int ni = 0; ni < 4; ni++) {
            const int col = bn + wn * 64 + ni * 16 + (lane & 15);
            const float bv = bias[col];
#pragma unroll
            for (int r = 0; r < 4; r++) {
                float val = (float)acc[mi][ni][r] * sAB + bv;
                if constexpr (EPI == EPI_G2_OUT) {
                    acc[mi][ni][r] = __float_as_int(val);
                } else {
                    float g = 0.5f * val *
                              (1.0f + erff(val * 0.70710678118654752440f));
                    lmax = fmaxf(lmax, fabsf(g));
                    acc[mi][ni][r] = __float_as_int(g);
                }
            }
        }
    }

    float enc = 0.f;
    if constexpr (EPI == EPI_G1_STORE_I16 || EPI == EPI_G1_MAXONLY) {
#pragma unroll
        for (int off = 32; off > 0; off >>= 1)
            lmax = fmaxf(lmax, __shfl_xor(lmax, off));
        if (lane == 0) red[wv] = lmax;
        __syncthreads();   // also: all waves done reading K-loop smem
        if (tid == 0) {
            float m = fmaxf(fmaxf(red[0], red[1]), fmaxf(red[2], red[3]));
            if constexpr (EPI == EPI_G1_STORE_I16) {
                tilescale[blockIdx.x * gridDim.y + blockIdx.y] = m;
                ts_sh = m;
            }
            atomicMax(maxslot, __float_as_uint(m));
        }
        __syncthreads();
        if constexpr (EPI == EPI_G1_STORE_I16)
            enc = 32767.f / fmaxf(ts_sh, 1e-20f);
    }

    // phase 2: stores
    if constexpr (EPI == EPI_G1_STORE_I16) {
        // transpose through LDS (reuse staging buffer), store staged int16:
        // within-block index = ni*256 + row15*16 + k15, 1KB-contiguous stores.
        int16_t* tl = (int16_t*)&smem[0][0][0];
        const int base16 = wv * 4096;
#pragma unroll
        for (int mi = 0; mi < 4; mi++)
#pragma unroll
            for (int ni = 0; ni < 4; ni++)
#pragma unroll
                for (int r = 0; r < 4; r++) {
                    float g = __int_as_float(acc[mi][ni][r]);
                    tl[base16 + mi * 1024 + ni * 256 +
                       ((lane >> 4) * 4 + r) * 16 + (lane & 15)] =
                        (int16_t)rintf(g * enc);
                }
        __syncthreads();
        const int kc = (bn >> 6) + wn;
#pragma unroll
        for (int mi = 0; mi < 4; mi++) {
            const int rb = (bm >> 4) + wm * 4 + mi;
            int16_t* dst = h16_out + ((size_t)rb * (N >> 6) + kc) * 1024;
            const int16_t* src = tl + base16 + mi * 1024;
            *(int4*)(dst + lane * 8)       = *(const int4*)(src + lane * 8);
            *(int4*)(dst + 512 + lane * 8) = *(const int4*)(src + 512 + lane * 8);
        }
    } else if constexpr (EPI != EPI_G1_MAXONLY) {
#pragma unroll
        for (int mi = 0; mi < 4; mi++) {
            const int row0 = bm + wm * 64 + mi * 16 + (lane >> 4) * 4;
#pragma unroll
            for (int ni = 0; ni < 4; ni++) {
                const int col = bn + wn * 64 + ni * 16 + (lane & 15);
#pragma unroll
                for (int r = 0; r < 4; r++) {
                    const int row = row0 + r;
                    float g = __int_as_float(acc[mi][ni][r]);
                    if constexpr (EPI == EPI_G2_OUT) {
                        out[(size_t)row * N + col] = g;
                    } else {  // EPI_G1_QUANT fallback: staged int8 scatter
                        float qv = fminf(fmaxf(rintf(g / sc_q), -127.f), 127.f);
                        size_t off = ((size_t)(row >> 4) * (N >> 6) + (col >> 6)) * 1024
                                   + ((col >> 4) & 3) * 256 + (row & 15) * 16 + (col & 15);
                        q_out[off] = (int8_t)qv;
                    }
                }
            }
        }
    }
}

// ---------------------------------------------------------------------------

extern "C" void kernel_launch(void* const* d_in, const int* in_sizes, int n_in,
                              void* d_out, int out_size, void* d_ws, size_t ws_size,
                              hipStream_t stream) {
    const float* x  = (const float*)d_in[0];  // (4,4096,1024)
    const float* w1 = (const float*)d_in[1];  // (4096,1024)
    const float* b1 = (const float*)d_in[2];  // (4096,)
    const float* w2 = (const float*)d_in[3];  // (1024,4096)
    const float* b2 = (const float*)d_in[4];  // (1024,)
    float* out = (float*)d_out;               // (4,4096,1024) fp32

    const int D = 1024, H = 4096;
    const int Mrows = 4 * 4096;  // 16384

    // ---- workspace layout ----
    uintptr_t ws = (uintptr_t)d_ws;
    unsigned int* slots = (unsigned int*)ws;   // [0]=|x| [1]=|w1| [2]=|w2| [3]=|h|
    const float* slotf = (const float*)ws;
    float* tiles = (float*)(ws + 256);                 // 4096 tile scales
    int8_t* xq  = (int8_t*)(ws + 256 + 65536);         // staged 16 MB
    int8_t* w1q = xq + (size_t)Mrows * D;              // staged 4 MB
    int8_t* w2q = w1q + (size_t)H * D;                 // staged 4 MB
    int8_t* hq  = w2q + (size_t)D * H;                 // staged 64 MB
    int16_t* h16 = (int16_t*)(hq + (size_t)Mrows * H); // staged 128 MB
    const size_t need_i16 =
        256 + 65536 + (size_t)Mrows * D + 2u * (size_t)H * D +
        (size_t)Mrows * H + (size_t)Mrows * H * sizeof(int16_t);  // ~216 MB
    const bool use_store = ws_size >= need_i16;  // constant per session

    // ---- scales ----
    init_slots<<<dim3(1), dim3(64), 0, stream>>>(slots);
    absmax_kernel<<<dim3(1024), dim3(256), 0, stream>>>(
        (const float4*)x, Mrows * D / 4, slots + 0);
    absmax_kernel<<<dim3(256), dim3(256), 0, stream>>>(
        (const float4*)w1, H * D / 4, slots + 1);
    absmax_kernel<<<dim3(256), dim3(256), 0, stream>>>(
        (const float4*)w2, D * H / 4, slots + 2);

    // ---- quantize + stage inputs ----
    quant_stage_kernel<<<dim3(1024), dim3(256), 0, stream>>>(
        x, 4, (Mrows / 16) * (D / 64), slotf + 0, xq);
    quant_stage_kernel<<<dim3(256), dim3(256), 0, stream>>>(
        w1, 4, (H / 16) * (D / 64), slotf + 1, w1q);
    quant_stage_kernel<<<dim3(256), dim3(256), 0, stream>>>(
        w2, 6, (D / 16) * (H / 64), slotf + 2, w2q);

    // ---- GEMM1: (16384x1024)·(4096x1024)^T + b1, GELU ----
    dim3 g1(Mrows / 128, H / 128);  // (128, 32), M fast
    if (use_store) {
        gemm_i8_kernel<EPI_G1_STORE_I16><<<g1, dim3(256), 0, stream>>>(
            xq, w1q, H, D, slotf + 0, slotf + 1, b1,
            h16, tiles, slots + 3, nullptr, nullptr, nullptr);
        quant_h_kernel<<<dim3(2048), dim3(256), 0, stream>>>(
            (const short8*)h16, tiles, slotf + 3, (char8*)hq, Mrows * H / 8);
    } else {
        gemm_i8_kernel<EPI_G1_MAXONLY><<<g1, dim3(256), 0, stream>>>(
            xq, w1q, H, D, slotf + 0, slotf + 1, b1,
            nullptr, nullptr, slots + 3, nullptr, nullptr, nullptr);
        gemm_i8_kernel<EPI_G1_QUANT><<<g1, dim3(256), 0, stream>>>(
            xq, w1q, H, D, slotf + 0, slotf + 1, b1,
            nullptr, nullptr, nullptr, slotf + 3, hq, nullptr);
    }

    // ---- GEMM2: (16384x4096)·(1024x4096)^T + b2 -> out ----
    dim3 g2(Mrows / 128, D / 128);  // (128, 8), M fast
    gemm_i8_kernel<EPI_G2_OUT><<<g2, dim3(256), 0, stream>>>(
        hq, w2q, D, H, slotf + 3, slotf + 2, b2,
        nullptr, nullptr, nullptr, nullptr, nullptr, out);
}

// Round 5
// 473.961 us; speedup vs baseline: 1.1814x; 1.1814x over previous
//
#include <hip/hip_runtime.h>
#include <hip/hip_bf16.h>
#include <math.h>
#include <stdint.h>

// ---------------------------------------------------------------------------
// HMQ MLP: fake-quant(int8) GEMM1 + bias + exact GELU -> fake-quant -> GEMM2
// int8 MFMA (mfma_i32_16x16x64_i8), exact int32 accumulation.
// R5: BARRIER-FREE K-loop. Operands are pre-staged fragment-major, so MFMA
// fragments are loaded DIRECTLY global->VGPR (coalesced dwordx4), ping-pong
// double-buffered in registers. No LDS, no __syncthreads, no vmcnt(0) drain
// (the m97-plateau mechanism). Epilogue uses branch-free A&S erf (libm erff
// was ~90us of VALU in GEMM1).
// ---------------------------------------------------------------------------

typedef int    v4i    __attribute__((ext_vector_type(4)));
typedef short  short8 __attribute__((ext_vector_type(8)));
typedef int8_t char8  __attribute__((ext_vector_type(8)));

#define QMAXF 127.0f

// branch-free exact-enough GELU: erf via Abramowitz-Stegun 7.1.26, |eps|<2e-7
__device__ __forceinline__ float gelu_exact(float v) {
    float z = fabsf(v) * 0.70710678118654752440f;
    float t = __builtin_amdgcn_rcpf(fmaf(0.3275911f, z, 1.0f));
    float p = fmaf(fmaf(fmaf(fmaf(1.061405429f, t, -1.453152027f), t,
                             1.421413741f), t, -0.284496736f), t,
                   0.254829592f) * t;
    float e = __expf(-z * z);
    float erfz = fmaf(-p, e, 1.0f);
    float erfv = v < 0.f ? -erfz : erfz;
    return 0.5f * v * (1.0f + erfv);
}

// ---------------- init: zero the scale slots ----------------
__global__ void init_slots(unsigned int* slots) {
    if (threadIdx.x < 8) slots[threadIdx.x] = 0u;
}

// ---------------- absmax reduction (fp32, float4) ----------------
__global__ void absmax_kernel(const float4* __restrict__ t, int n4,
                              unsigned int* __restrict__ slot) {
    float m = 0.f;
    int stride = gridDim.x * blockDim.x;
    for (int i = blockIdx.x * blockDim.x + threadIdx.x; i < n4; i += stride) {
        float4 v = t[i];
        m = fmaxf(m, fmaxf(fmaxf(fabsf(v.x), fabsf(v.y)),
                           fmaxf(fabsf(v.z), fabsf(v.w))));
    }
#pragma unroll
    for (int off = 32; off > 0; off >>= 1)
        m = fmaxf(m, __shfl_xor(m, off));
    if ((threadIdx.x & 63) == 0)
        atomicMax(slot, __float_as_uint(m));  // vals >= 0: uint order == float order
}

// ---------------- quantize fp32 -> staged int8 ----------------
// One wave per 1KB block (rb, kc): lane L handles row15=L&15, chunk=L>>4.
__global__ void quant_stage_kernel(const float* __restrict__ x, int kshift,
                                   int nblocks, const float* __restrict__ slot,
                                   int8_t* __restrict__ q) {
    const float s = fmaxf(*slot, 1e-8f) / QMAXF;
    const int lane = threadIdx.x & 63;
    const int wave0 = (blockIdx.x * blockDim.x + threadIdx.x) >> 6;
    const int nwaves = (gridDim.x * blockDim.x) >> 6;
    const int nkb = 1 << kshift;  // K/64
    for (int wb = wave0; wb < nblocks; wb += nwaves) {
        const int rb = wb >> kshift;
        const int kc = wb & (nkb - 1);
        const int row = rb * 16 + (lane & 15);
        const int k0  = kc * 64 + (lane >> 4) * 16;
        const float4* src = (const float4*)(x + ((size_t)row << (kshift + 6)) + k0);
        int8_t tmp[16];
#pragma unroll
        for (int j = 0; j < 4; j++) {
            float4 v = src[j];
            tmp[j*4+0] = (int8_t)fminf(fmaxf(rintf(v.x / s), -127.f), 127.f);
            tmp[j*4+1] = (int8_t)fminf(fmaxf(rintf(v.y / s), -127.f), 127.f);
            tmp[j*4+2] = (int8_t)fminf(fmaxf(rintf(v.z / s), -127.f), 127.f);
            tmp[j*4+3] = (int8_t)fminf(fmaxf(rintf(v.w / s), -127.f), 127.f);
        }
        *(int4*)(q + (size_t)wb * 1024 + lane * 16) = *(const int4*)tmp;
    }
}

// ---------------- streaming: staged int16 h -> staged int8 hq ----------
__global__ void quant_h_kernel(const short8* __restrict__ h16s,
                               const float* __restrict__ tilescale,
                               const float* __restrict__ hslot,
                               char8* __restrict__ q, int n8) {
    const float sh = fmaxf(*hslot, 1e-8f) / QMAXF;
    int stride = gridDim.x * blockDim.x;
    for (int i = blockIdx.x * blockDim.x + threadIdx.x; i < n8; i += stride) {
        const int blk = i >> 7;            // (i*8)/1024
        const int rb = blk >> 6, kc = blk & 63;
        const int tile = (rb >> 3) * 32 + (kc >> 1);
        const float f = tilescale[tile] / (32767.f * sh);
        short8 v = h16s[i];
        char8 o;
#pragma unroll
        for (int j = 0; j < 8; j++)
            o[j] = (int8_t)fminf(fmaxf(rintf((float)v[j] * f), -127.f), 127.f);
        q[i] = o;
    }
}

// ---------------- int8 GEMM on staged operands, no LDS, no barriers -------
#define EPI_G1_STORE_I16 0   // g=gelu(..); tilemax; store staged int16
#define EPI_G1_MAXONLY   1   // g=gelu(..); atomicMax only (fallback)
#define EPI_G1_QUANT     2   // g=gelu(..); store staged int8 (fallback)
#define EPI_G2_OUT       3   // out = acc*s + b; store fp32 row-major

template <int EPI>
__global__ __launch_bounds__(256, 3) void gemm_i8_kernel(
    const int8_t* __restrict__ A, const int8_t* __restrict__ B,
    int N, int K,
    const float* __restrict__ slotA, const float* __restrict__ slotB,
    const float* __restrict__ bias,
    int16_t* __restrict__ h16_out,        // EPI 0 (staged layout)
    float* __restrict__ tilescale,        // EPI 0
    unsigned int* __restrict__ maxslot,   // EPI 0/1
    const float* __restrict__ hslot,      // EPI 2
    int8_t* __restrict__ q_out,           // EPI 2
    float* __restrict__ out)              // EPI 3
{
    __shared__ __align__(16) int16_t tl[16384];  // epilogue transpose only
    __shared__ float red[4];

    const int tid  = threadIdx.x;
    const int lane = tid & 63;
    const int wv   = tid >> 6;
    const int wm   = wv & 1;
    const int wn   = wv >> 1;

    const int bm = blockIdx.x * 128;   // M fast: co-resident blocks share B tiles
    const int bn = blockIdx.y * 128;
    const int nkb = K >> 6;

    const float sAB = (fmaxf(*slotA, 1e-8f) / QMAXF) *
                      (fmaxf(*slotB, 1e-8f) / QMAXF);

    v4i acc[4][4] = {};

    // Per-lane fragment base pointers into the staged layout.
    const size_t rbstride = (size_t)nkb * 1024;
    const int8_t* pA = A + (size_t)((bm >> 4) + wm * 4) * rbstride + lane * 16;
    const int8_t* pB = B + (size_t)((bn >> 4) + wn * 4) * rbstride + lane * 16;

    auto loadA = [&](v4i (&d)[4], int k) {
#pragma unroll
        for (int i = 0; i < 4; i++)
            d[i] = *(const v4i*)(pA + (size_t)i * rbstride + (size_t)k * 1024);
    };
    auto loadB = [&](v4i (&d)[4], int k) {
#pragma unroll
        for (int i = 0; i < 4; i++)
            d[i] = *(const v4i*)(pB + (size_t)i * rbstride + (size_t)k * 1024);
    };
    auto mfma_all = [&](v4i (&a)[4], v4i (&b)[4]) {
#pragma unroll
        for (int mi = 0; mi < 4; mi++)
#pragma unroll
            for (int ni = 0; ni < 4; ni++)
                acc[mi][ni] = __builtin_amdgcn_mfma_i32_16x16x64_i8(
                    a[mi], b[ni], acc[mi][ni], 0, 0, 0);
    };

    // register ping-pong pipeline, distance ~1 full MFMA phase, no barriers
    v4i a0[4], b0[4], a1[4], b1[4];
    loadA(a0, 0); loadB(b0, 0);
    loadA(a1, 1); loadB(b1, 1);
    int kt = 0;
    for (; kt + 2 < nkb; kt += 2) {
        mfma_all(a0, b0);
        loadA(a0, kt + 2); loadB(b0, kt + 2);
        mfma_all(a1, b1);
        loadA(a1, kt + 3); loadB(b1, kt + 3);
    }
    mfma_all(a0, b0);
    mfma_all(a1, b1);

    // ---------------- epilogue ----------------
    float sc_q = 0.f;
    if constexpr (EPI == EPI_G1_QUANT) sc_q = fmaxf(*hslot, 1e-8f) / QMAXF;
    float lmax = 0.f;

    // phase 1: dequant + bias (+ GELU); park result bits back into acc regs
#pragma unroll
    for (int mi = 0; mi < 4; mi++) {
#pragma unroll
        for (int ni = 0; ni < 4; ni++) {
            const int col = bn + wn * 64 + ni * 16 + (lane & 15);
            const float bv = bias[col];
#pragma unroll
            for (int r = 0; r < 4; r++) {
                float val = (float)acc[mi][ni][r] * sAB + bv;
                if constexpr (EPI == EPI_G2_OUT) {
                    acc[mi][ni][r] = __float_as_int(val);
                } else {
                    float g = gelu_exact(val);
                    lmax = fmaxf(lmax, fabsf(g));
                    acc[mi][ni][r] = __float_as_int(g);
                }
            }
        }
    }

    float enc = 0.f;
    if constexpr (EPI == EPI_G1_STORE_I16 || EPI == EPI_G1_MAXONLY) {
#pragma unroll
        for (int off = 32; off > 0; off >>= 1)
            lmax = fmaxf(lmax, __shfl_xor(lmax, off));
        if (lane == 0) red[wv] = lmax;
        __syncthreads();
        const float m = fmaxf(fmaxf(red[0], red[1]), fmaxf(red[2], red[3]));
        if (tid == 0) {
            if constexpr (EPI == EPI_G1_STORE_I16)
                tilescale[blockIdx.x * gridDim.y + blockIdx.y] = m;
            atomicMax(maxslot, __float_as_uint(m));
        }
        enc = 32767.f / fmaxf(m, 1e-20f);
    }

    // phase 2: stores
    if constexpr (EPI == EPI_G1_STORE_I16) {
        // transpose through LDS, store staged int16 (1KB-contiguous per instr)
        const int base16 = wv * 4096;
#pragma unroll
        for (int mi = 0; mi < 4; mi++)
#pragma unroll
            for (int ni = 0; ni < 4; ni++)
#pragma unroll
                for (int r = 0; r < 4; r++) {
                    float g = __int_as_float(acc[mi][ni][r]);
                    tl[base16 + mi * 1024 + ni * 256 +
                       ((lane >> 4) * 4 + r) * 16 + (lane & 15)] =
                        (int16_t)rintf(g * enc);
                }
        __syncthreads();
        const int kc = (bn >> 6) + wn;
#pragma unroll
        for (int mi = 0; mi < 4; mi++) {
            const int rb = (bm >> 4) + wm * 4 + mi;
            int16_t* dst = h16_out + ((size_t)rb * (N >> 6) + kc) * 1024;
            const int16_t* src = tl + base16 + mi * 1024;
            *(int4*)(dst + lane * 8)       = *(const int4*)(src + lane * 8);
            *(int4*)(dst + 512 + lane * 8) = *(const int4*)(src + 512 + lane * 8);
        }
    } else if constexpr (EPI != EPI_G1_MAXONLY) {
#pragma unroll
        for (int mi = 0; mi < 4; mi++) {
            const int row0 = bm + wm * 64 + mi * 16 + (lane >> 4) * 4;
#pragma unroll
            for (int ni = 0; ni < 4; ni++) {
                const int col = bn + wn * 64 + ni * 16 + (lane & 15);
#pragma unroll
                for (int r = 0; r < 4; r++) {
                    const int row = row0 + r;
                    float g = __int_as_float(acc[mi][ni][r]);
                    if constexpr (EPI == EPI_G2_OUT) {
                        out[(size_t)row * N + col] = g;
                    } else {  // EPI_G1_QUANT fallback: staged int8 scatter
                        float qv = fminf(fmaxf(rintf(g / sc_q), -127.f), 127.f);
                        size_t off = ((size_t)(row >> 4) * (N >> 6) + (col >> 6)) * 1024
                                   + ((col >> 4) & 3) * 256 + (row & 15) * 16 + (col & 15);
                        q_out[off] = (int8_t)qv;
                    }
                }
            }
        }
    }
}

// ---------------------------------------------------------------------------

extern "C" void kernel_launch(void* const* d_in, const int* in_sizes, int n_in,
                              void* d_out, int out_size, void* d_ws, size_t ws_size,
                              hipStream_t stream) {
    const float* x  = (const float*)d_in[0];  // (4,4096,1024)
    const float* w1 = (const float*)d_in[1];  // (4096,1024)
    const float* b1 = (const float*)d_in[2];  // (4096,)
    const float* w2 = (const float*)d_in[3];  // (1024,4096)
    const float* b2 = (const float*)d_in[4];  // (1024,)
    float* out = (float*)d_out;               // (4,4096,1024) fp32

    const int D = 1024, H = 4096;
    const int Mrows = 4 * 4096;  // 16384

    // ---- workspace layout ----
    uintptr_t ws = (uintptr_t)d_ws;
    unsigned int* slots = (unsigned int*)ws;   // [0]=|x| [1]=|w1| [2]=|w2| [3]=|h|
    const float* slotf = (const float*)ws;
    float* tiles = (float*)(ws + 256);                 // 4096 tile scales
    int8_t* xq  = (int8_t*)(ws + 256 + 65536);         // staged 16 MB
    int8_t* w1q = xq + (size_t)Mrows * D;              // staged 4 MB
    int8_t* w2q = w1q + (size_t)H * D;                 // staged 4 MB
    int8_t* hq  = w2q + (size_t)D * H;                 // staged 64 MB
    int16_t* h16 = (int16_t*)(hq + (size_t)Mrows * H); // staged 128 MB
    const size_t need_i16 =
        256 + 65536 + (size_t)Mrows * D + 2u * (size_t)H * D +
        (size_t)Mrows * H + (size_t)Mrows * H * sizeof(int16_t);  // ~216 MB
    const bool use_store = ws_size >= need_i16;  // constant per session

    // ---- scales ----
    init_slots<<<dim3(1), dim3(64), 0, stream>>>(slots);
    absmax_kernel<<<dim3(1024), dim3(256), 0, stream>>>(
        (const float4*)x, Mrows * D / 4, slots + 0);
    absmax_kernel<<<dim3(256), dim3(256), 0, stream>>>(
        (const float4*)w1, H * D / 4, slots + 1);
    absmax_kernel<<<dim3(256), dim3(256), 0, stream>>>(
        (const float4*)w2, D * H / 4, slots + 2);

    // ---- quantize + stage inputs ----
    quant_stage_kernel<<<dim3(1024), dim3(256), 0, stream>>>(
        x, 4, (Mrows / 16) * (D / 64), slotf + 0, xq);
    quant_stage_kernel<<<dim3(256), dim3(256), 0, stream>>>(
        w1, 4, (H / 16) * (D / 64), slotf + 1, w1q);
    quant_stage_kernel<<<dim3(256), dim3(256), 0, stream>>>(
        w2, 6, (D / 16) * (H / 64), slotf + 2, w2q);

    // ---- GEMM1: (16384x1024)·(4096x1024)^T + b1, GELU ----
    dim3 g1(Mrows / 128, H / 128);  // (128, 32), M fast
    if (use_store) {
        gemm_i8_kernel<EPI_G1_STORE_I16><<<g1, dim3(256), 0, stream>>>(
            xq, w1q, H, D, slotf + 0, slotf + 1, b1,
            h16, tiles, slots + 3, nullptr, nullptr, nullptr);
        quant_h_kernel<<<dim3(2048), dim3(256), 0, stream>>>(
            (const short8*)h16, tiles, slotf + 3, (char8*)hq, Mrows * H / 8);
    } else {
        gemm_i8_kernel<EPI_G1_MAXONLY><<<g1, dim3(256), 0, stream>>>(
            xq, w1q, H, D, slotf + 0, slotf + 1, b1,
            nullptr, nullptr, slots + 3, nullptr, nullptr, nullptr);
        gemm_i8_kernel<EPI_G1_QUANT><<<g1, dim3(256), 0, stream>>>(
            xq, w1q, H, D, slotf + 0, slotf + 1, b1,
            nullptr, nullptr, nullptr, slotf + 3, hq, nullptr);
    }

    // ---- GEMM2: (16384x4096)·(1024x4096)^T + b2 -> out ----
    dim3 g2(Mrows / 128, D / 128);  // (128, 8), M fast
    gemm_i8_kernel<EPI_G2_OUT><<<g2, dim3(256), 0, stream>>>(
        hq, w2q, D, H, slotf + 3, slotf + 2, b2,
        nullptr, nullptr, nullptr, nullptr, nullptr, out);
}

// Round 6
// 461.711 us; speedup vs baseline: 1.2127x; 1.0265x over previous
//
#include <hip/hip_runtime.h>
#include <hip/hip_bf16.h>
#include <math.h>
#include <stdint.h>

// ---------------------------------------------------------------------------
// HMQ MLP: fake-quant(int8) GEMM1 + bias + exact GELU -> fake-quant -> GEMM2
// int8 MFMA (mfma_i32_16x16x64_i8), exact int32 accumulation.
// R6: wave tile widened to 64x128 (4x8 acc tiles) -> 32 MFMA per 12KB of
// loads (was 16 per 8KB): VMEM volume x0.75, longer MFMA phases cover load
// latency. Block 128x256, launch_bounds(256,2). quant_stage reads made
// coalesced via wave-private LDS transpose (was lane-stride-4KB scatter).
// ---------------------------------------------------------------------------

typedef int    v4i    __attribute__((ext_vector_type(4)));
typedef short  short8 __attribute__((ext_vector_type(8)));
typedef int8_t char8  __attribute__((ext_vector_type(8)));

#define QMAXF 127.0f

// branch-free GELU: erf via Abramowitz-Stegun 7.1.26, |eps|<2e-7
__device__ __forceinline__ float gelu_exact(float v) {
    float z = fabsf(v) * 0.70710678118654752440f;
    float t = __builtin_amdgcn_rcpf(fmaf(0.3275911f, z, 1.0f));
    float p = fmaf(fmaf(fmaf(fmaf(1.061405429f, t, -1.453152027f), t,
                             1.421413741f), t, -0.284496736f), t,
                   0.254829592f) * t;
    float e = __expf(-z * z);
    float erfz = fmaf(-p, e, 1.0f);
    float erfv = v < 0.f ? -erfz : erfz;
    return 0.5f * v * (1.0f + erfv);
}

// ---------------- init: zero the scale slots ----------------
__global__ void init_slots(unsigned int* slots) {
    if (threadIdx.x < 8) slots[threadIdx.x] = 0u;
}

// ---------------- absmax reduction (fp32, float4) ----------------
__global__ void absmax_kernel(const float4* __restrict__ t, int n4,
                              unsigned int* __restrict__ slot) {
    float m = 0.f;
    int stride = gridDim.x * blockDim.x;
    for (int i = blockIdx.x * blockDim.x + threadIdx.x; i < n4; i += stride) {
        float4 v = t[i];
        m = fmaxf(m, fmaxf(fmaxf(fabsf(v.x), fabsf(v.y)),
                           fmaxf(fabsf(v.z), fabsf(v.w))));
    }
#pragma unroll
    for (int off = 32; off > 0; off >>= 1)
        m = fmaxf(m, __shfl_xor(m, off));
    if ((threadIdx.x & 63) == 0)
        atomicMax(slot, __float_as_uint(m));  // vals >= 0: uint order == float order
}

// ---------------- quantize fp32 -> staged int8, coalesced ----------------
// One wave per 1KB-dest block (16 rows x 64 k). Reads 4x 1KB instrs covering
// 4 full 256B row-segments each (coalesced); transposes via wave-private LDS;
// writes 1KB contiguous.
__global__ void quant_stage_kernel(const float* __restrict__ x, int kshift,
                                   int nblocks, const float* __restrict__ slot,
                                   int8_t* __restrict__ q) {
    __shared__ float qt[4][1088];  // per wave: 16 rows x 68 (pad 4) floats
    const float s = fmaxf(*slot, 1e-8f) / QMAXF;
    const int lane = threadIdx.x & 63;
    const int wv   = threadIdx.x >> 6;
    const int wave0 = (blockIdx.x * blockDim.x + threadIdx.x) >> 6;
    const int nwaves = (gridDim.x * blockDim.x) >> 6;
    const int nkb = 1 << kshift;  // K/64
    const int K = 64 << kshift;
    float* tw = &qt[wv][0];
    for (int wb = wave0; wb < nblocks; wb += nwaves) {
        const int rb = wb >> kshift;
        const int kc = wb & (nkb - 1);
        // coalesced read: instr j covers rows rb*16+j*4..+3, 256B per row
#pragma unroll
        for (int j = 0; j < 4; j++) {
            const int row = rb * 16 + j * 4 + (lane >> 4);
            float4 v = *(const float4*)(x + (size_t)row * K + kc * 64 + (lane & 15) * 4);
            *(float4*)(tw + (j * 4 + (lane >> 4)) * 68 + (lane & 15) * 4) = v;
        }
        // fragment gather: lane -> row15 = lane&15, k-chunk = (lane>>4)*16
        int8_t tmp[16];
#pragma unroll
        for (int t = 0; t < 4; t++) {
            float4 v = *(const float4*)(tw + (lane & 15) * 68 + (lane >> 4) * 16 + t * 4);
            tmp[t*4+0] = (int8_t)fminf(fmaxf(rintf(v.x / s), -127.f), 127.f);
            tmp[t*4+1] = (int8_t)fminf(fmaxf(rintf(v.y / s), -127.f), 127.f);
            tmp[t*4+2] = (int8_t)fminf(fmaxf(rintf(v.z / s), -127.f), 127.f);
            tmp[t*4+3] = (int8_t)fminf(fmaxf(rintf(v.w / s), -127.f), 127.f);
        }
        *(int4*)(q + (size_t)wb * 1024 + lane * 16) = *(const int4*)tmp;
    }
}

// ---------------- streaming: staged int16 h -> staged int8 hq ----------
__global__ void quant_h_kernel(const short8* __restrict__ h16s,
                               const float* __restrict__ tilescale,
                               const float* __restrict__ hslot,
                               char8* __restrict__ q, int n8) {
    const float sh = fmaxf(*hslot, 1e-8f) / QMAXF;
    int stride = gridDim.x * blockDim.x;
    for (int i = blockIdx.x * blockDim.x + threadIdx.x; i < n8; i += stride) {
        const int blk = i >> 7;            // (i*8)/1024
        const int rb = blk >> 6, kc = blk & 63;
        const int tile = (rb >> 3) * 32 + (kc >> 1);
        const float f = tilescale[tile] / (32767.f * sh);
        short8 v = h16s[i];
        char8 o;
#pragma unroll
        for (int j = 0; j < 8; j++)
            o[j] = (int8_t)fminf(fmaxf(rintf((float)v[j] * f), -127.f), 127.f);
        q[i] = o;
    }
}

// ---------------- int8 GEMM on staged operands, no LDS in K-loop ----------
#define EPI_G1_STORE_I16 0   // g=gelu(..); tilemax; store staged int16
#define EPI_G1_MAXONLY   1   // g=gelu(..); atomicMax only (fallback)
#define EPI_G1_QUANT     2   // g=gelu(..); store staged int8 (fallback)
#define EPI_G2_OUT       3   // out = acc*s + b; store fp32 row-major

template <int EPI>
__global__ __launch_bounds__(256, 2) void gemm_i8_kernel(
    const int8_t* __restrict__ A, const int8_t* __restrict__ B,
    int N, int K,
    const float* __restrict__ slotA, const float* __restrict__ slotB,
    const float* __restrict__ bias,
    int16_t* __restrict__ h16_out,        // EPI 0 (staged layout)
    float* __restrict__ tilescale,        // EPI 0
    unsigned int* __restrict__ maxslot,   // EPI 0/1
    const float* __restrict__ hslot,      // EPI 2
    int8_t* __restrict__ q_out,           // EPI 2
    float* __restrict__ out)              // EPI 3
{
    __shared__ __align__(16) int16_t tl[16384];  // epilogue transpose (32 KB)
    __shared__ float red[4];

    const int tid  = threadIdx.x;
    const int lane = tid & 63;
    const int wv   = tid >> 6;
    const int wm   = wv & 1;    // 64-row half
    const int wn   = wv >> 1;   // 128-col half

    const int bm = blockIdx.x * 128;   // M fast
    const int bn = blockIdx.y * 256;
    const int nkb = K >> 6;

    const float sAB = (fmaxf(*slotA, 1e-8f) / QMAXF) *
                      (fmaxf(*slotB, 1e-8f) / QMAXF);

    v4i acc[4][8] = {};

    const size_t rbstride = (size_t)nkb * 1024;
    const int8_t* pA = A + (size_t)((bm >> 4) + wm * 4) * rbstride + lane * 16;
    const int8_t* pB = B + (size_t)((bn >> 4) + wn * 8) * rbstride + lane * 16;

    auto loadA = [&](v4i (&d)[4], int k) {
#pragma unroll
        for (int i = 0; i < 4; i++)
            d[i] = *(const v4i*)(pA + (size_t)i * rbstride + (size_t)k * 1024);
    };
    auto loadB = [&](v4i (&d)[8], int k) {
#pragma unroll
        for (int i = 0; i < 8; i++)
            d[i] = *(const v4i*)(pB + (size_t)i * rbstride + (size_t)k * 1024);
    };
    auto mfma_all = [&](v4i (&a)[4], v4i (&b)[8]) {
#pragma unroll
        for (int mi = 0; mi < 4; mi++)
#pragma unroll
            for (int ni = 0; ni < 8; ni++)
                acc[mi][ni] = __builtin_amdgcn_mfma_i32_16x16x64_i8(
                    a[mi], b[ni], acc[mi][ni], 0, 0, 0);
    };

    // register ping-pong pipeline, no barriers
    v4i a0[4], a1[4];
    v4i b0[8], b1[8];
    loadA(a0, 0); loadB(b0, 0);
    loadA(a1, 1); loadB(b1, 1);
    int kt = 0;
    for (; kt + 2 < nkb; kt += 2) {
        mfma_all(a0, b0);
        loadA(a0, kt + 2); loadB(b0, kt + 2);
        mfma_all(a1, b1);
        loadA(a1, kt + 3); loadB(b1, kt + 3);
    }
    mfma_all(a0, b0);
    mfma_all(a1, b1);

    // ---------------- epilogue ----------------
    float sc_q = 0.f;
    if constexpr (EPI == EPI_G1_QUANT) sc_q = fmaxf(*hslot, 1e-8f) / QMAXF;
    float lmax = 0.f;

    // phase 1: dequant + bias (+ GELU); park result bits back into acc regs
#pragma unroll
    for (int mi = 0; mi < 4; mi++) {
#pragma unroll
        for (int ni = 0; ni < 8; ni++) {
            const int col = bn + wn * 128 + ni * 16 + (lane & 15);
            const float bv = bias[col];
#pragma unroll
            for (int r = 0; r < 4; r++) {
                float val = (float)acc[mi][ni][r] * sAB + bv;
                if constexpr (EPI == EPI_G2_OUT) {
                    acc[mi][ni][r] = __float_as_int(val);
                } else {
                    float g = gelu_exact(val);
                    lmax = fmaxf(lmax, fabsf(g));
                    acc[mi][ni][r] = __float_as_int(g);
                }
            }
        }
    }

    float enc = 0.f;
    if constexpr (EPI == EPI_G1_STORE_I16 || EPI == EPI_G1_MAXONLY) {
#pragma unroll
        for (int off = 32; off > 0; off >>= 1)
            lmax = fmaxf(lmax, __shfl_xor(lmax, off));
        if (lane == 0) red[wv] = lmax;
        __syncthreads();
        const float m = fmaxf(fmaxf(red[0], red[1]), fmaxf(red[2], red[3]));
        if (tid == 0) {
            if constexpr (EPI == EPI_G1_STORE_I16) {
                const int tbase = blockIdx.x * (gridDim.y * 2) + blockIdx.y * 2;
                tilescale[tbase]     = m;
                tilescale[tbase + 1] = m;
            }
            atomicMax(maxslot, __float_as_uint(m));
        }
        enc = 32767.f / fmaxf(m, 1e-20f);
    }

    // phase 2: stores
    if constexpr (EPI == EPI_G1_STORE_I16) {
        // two 32KB halves; wave-private LDS regions -> no barriers needed
        const int r16 = (lane >> 4) * 4;
        const int c15 = lane & 15;
#pragma unroll
        for (int half = 0; half < 2; half++) {
#pragma unroll
            for (int mi = 0; mi < 4; mi++)
#pragma unroll
                for (int nih = 0; nih < 4; nih++) {
                    const int ni = half * 4 + nih;
#pragma unroll
                    for (int r = 0; r < 4; r++) {
                        float g = __int_as_float(acc[mi][ni][r]);
                        tl[wv * 4096 + mi * 1024 + nih * 256 + (r16 + r) * 16 + c15] =
                            (int16_t)rintf(g * enc);
                    }
                }
            const int kc = (bn >> 6) + wn * 2 + half;
#pragma unroll
            for (int mi = 0; mi < 4; mi++) {
                const int rb = (bm >> 4) + wm * 4 + mi;
                int16_t* dst = h16_out + ((size_t)rb * (N >> 6) + kc) * 1024;
                const int16_t* src = tl + wv * 4096 + mi * 1024;
                *(int4*)(dst + lane * 8)       = *(const int4*)(src + lane * 8);
                *(int4*)(dst + 512 + lane * 8) = *(const int4*)(src + 512 + lane * 8);
            }
        }
    } else if constexpr (EPI != EPI_G1_MAXONLY) {
#pragma unroll
        for (int mi = 0; mi < 4; mi++) {
            const int row0 = bm + wm * 64 + mi * 16 + (lane >> 4) * 4;
#pragma unroll
            for (int ni = 0; ni < 8; ni++) {
                const int col = bn + wn * 128 + ni * 16 + (lane & 15);
#pragma unroll
                for (int r = 0; r < 4; r++) {
                    const int row = row0 + r;
                    float g = __int_as_float(acc[mi][ni][r]);
                    if constexpr (EPI == EPI_G2_OUT) {
                        out[(size_t)row * N + col] = g;
                    } else {  // EPI_G1_QUANT fallback: staged int8 scatter
                        float qv = fminf(fmaxf(rintf(g / sc_q), -127.f), 127.f);
                        size_t off = ((size_t)(row >> 4) * (N >> 6) + (col >> 6)) * 1024
                                   + ((col >> 4) & 3) * 256 + (row & 15) * 16 + (col & 15);
                        q_out[off] = (int8_t)qv;
                    }
                }
            }
        }
    }
}

// ---------------------------------------------------------------------------

extern "C" void kernel_launch(void* const* d_in, const int* in_sizes, int n_in,
                              void* d_out, int out_size, void* d_ws, size_t ws_size,
                              hipStream_t stream) {
    const float* x  = (const float*)d_in[0];  // (4,4096,1024)
    const float* w1 = (const float*)d_in[1];  // (4096,1024)
    const float* b1 = (const float*)d_in[2];  // (4096,)
    const float* w2 = (const float*)d_in[3];  // (1024,4096)
    const float* b2 = (const float*)d_in[4];  // (1024,)
    float* out = (float*)d_out;               // (4,4096,1024) fp32

    const int D = 1024, H = 4096;
    const int Mrows = 4 * 4096;  // 16384

    // ---- workspace layout ----
    uintptr_t ws = (uintptr_t)d_ws;
    unsigned int* slots = (unsigned int*)ws;   // [0]=|x| [1]=|w1| [2]=|w2| [3]=|h|
    const float* slotf = (const float*)ws;
    float* tiles = (float*)(ws + 256);                 // 4096 tile scales
    int8_t* xq  = (int8_t*)(ws + 256 + 65536);         // staged 16 MB
    int8_t* w1q = xq + (size_t)Mrows * D;              // staged 4 MB
    int8_t* w2q = w1q + (size_t)H * D;                 // staged 4 MB
    int8_t* hq  = w2q + (size_t)D * H;                 // staged 64 MB
    int16_t* h16 = (int16_t*)(hq + (size_t)Mrows * H); // staged 128 MB
    const size_t need_i16 =
        256 + 65536 + (size_t)Mrows * D + 2u * (size_t)H * D +
        (size_t)Mrows * H + (size_t)Mrows * H * sizeof(int16_t);  // ~216 MB
    const bool use_store = ws_size >= need_i16;  // constant per session

    // ---- scales ----
    init_slots<<<dim3(1), dim3(64), 0, stream>>>(slots);
    absmax_kernel<<<dim3(1024), dim3(256), 0, stream>>>(
        (const float4*)x, Mrows * D / 4, slots + 0);
    absmax_kernel<<<dim3(256), dim3(256), 0, stream>>>(
        (const float4*)w1, H * D / 4, slots + 1);
    absmax_kernel<<<dim3(256), dim3(256), 0, stream>>>(
        (const float4*)w2, D * H / 4, slots + 2);

    // ---- quantize + stage inputs (coalesced) ----
    quant_stage_kernel<<<dim3(1024), dim3(256), 0, stream>>>(
        x, 4, (Mrows / 16) * (D / 64), slotf + 0, xq);
    quant_stage_kernel<<<dim3(256), dim3(256), 0, stream>>>(
        w1, 4, (H / 16) * (D / 64), slotf + 1, w1q);
    quant_stage_kernel<<<dim3(256), dim3(256), 0, stream>>>(
        w2, 6, (D / 16) * (H / 64), slotf + 2, w2q);

    // ---- GEMM1: (16384x1024)·(4096x1024)^T + b1, GELU ----
    dim3 g1(Mrows / 128, H / 256);  // (128, 16), M fast
    if (use_store) {
        gemm_i8_kernel<EPI_G1_STORE_I16><<<g1, dim3(256), 0, stream>>>(
            xq, w1q, H, D, slotf + 0, slotf + 1, b1,
            h16, tiles, slots + 3, nullptr, nullptr, nullptr);
        quant_h_kernel<<<dim3(2048), dim3(256), 0, stream>>>(
            (const short8*)h16, tiles, slotf + 3, (char8*)hq, Mrows * H / 8);
    } else {
        gemm_i8_kernel<EPI_G1_MAXONLY><<<g1, dim3(256), 0, stream>>>(
            xq, w1q, H, D, slotf + 0, slotf + 1, b1,
            nullptr, nullptr, slots + 3, nullptr, nullptr, nullptr);
        gemm_i8_kernel<EPI_G1_QUANT><<<g1, dim3(256), 0, stream>>>(
            xq, w1q, H, D, slotf + 0, slotf + 1, b1,
            nullptr, nullptr, nullptr, slotf + 3, hq, nullptr);
    }

    // ---- GEMM2: (16384x4096)·(1024x4096)^T + b2 -> out ----
    dim3 g2(Mrows / 128, D / 256);  // (128, 4), M fast
    gemm_i8_kernel<EPI_G2_OUT><<<g2, dim3(256), 0, stream>>>(
        hq, w2q, D, H, slotf + 3, slotf + 2, b2,
        nullptr, nullptr, nullptr, nullptr, nullptr, out);
}